// Round 1
// baseline (109.274 us; speedup 1.0000x reference)
//
#include <hip/hip_runtime.h>
#include <hip/hip_bf16.h>
#include <stdint.h>

#define LEAKY_ALPHA 0.2f
#define NEG_BIG (-1e30f)

using f32x4 = __attribute__((ext_vector_type(4))) float;
using u32x4 = __attribute__((ext_vector_type(4))) unsigned int;
using i32x4 = __attribute__((ext_vector_type(4))) int;
using s16x8 = __attribute__((ext_vector_type(8))) short;

static __device__ __forceinline__ unsigned short f2bf(float x) {
  __hip_bfloat16 b = __float2bfloat16(x);
  return __builtin_bit_cast(unsigned short, b);
}

// ---------------------------------------------------------------------------
// Kernel A: Wh = h @ W (fp32), emit WhT (bf16, [B][256 o][2048 q]) and
// s[b*N+q] = rowsum(Wh) (fp32). 512 blocks x 256 thr, 32 rows/block.
// ---------------------------------------------------------------------------
__global__ __launch_bounds__(256, 2) void gat_wh(
    const float* __restrict__ h, const float* __restrict__ W,
    __hip_bfloat16* __restrict__ WhT, float* __restrict__ s)
{
  const int F = 256;
  const int r0 = blockIdx.x * 32;       // global row base (16384 rows total)
  const int t = threadIdx.x;
  const int wid = t >> 6;
  const int lane = t & 63;
  const int c = lane * 4;               // output col base (4 cols/thread)

  __shared__ float hs[32][32];
  __shared__ float Ws[32][256];

  f32x4 acc[8];
#pragma unroll
  for (int i = 0; i < 8; ++i) acc[i] = (f32x4)(0.f);

  for (int k0 = 0; k0 < F; k0 += 32) {
    __syncthreads();
    {
      const int row = t >> 3, kc = (t & 7) * 4;
      *(f32x4*)&hs[row][kc] =
          *(const f32x4*)&h[(size_t)(r0 + row) * F + (k0 + kc)];
    }
#pragma unroll
    for (int j = 0; j < 8; ++j) {
      const int flat = t + j * 256;
      const int kk = flat >> 6, o4 = (flat & 63) * 4;
      *(f32x4*)&Ws[kk][o4] = *(const f32x4*)&W[(size_t)(k0 + kk) * F + o4];
    }
    __syncthreads();
#pragma unroll
    for (int kk4 = 0; kk4 < 8; ++kk4) {
      const f32x4 wv0 = *(const f32x4*)&Ws[kk4 * 4 + 0][c];
      const f32x4 wv1 = *(const f32x4*)&Ws[kk4 * 4 + 1][c];
      const f32x4 wv2 = *(const f32x4*)&Ws[kk4 * 4 + 2][c];
      const f32x4 wv3 = *(const f32x4*)&Ws[kk4 * 4 + 3][c];
#pragma unroll
      for (int i = 0; i < 8; ++i) {
        const f32x4 h4 = *(const f32x4*)&hs[wid * 8 + i][kk4 * 4];
        acc[i] += wv0 * h4[0];
        acc[i] += wv1 * h4[1];
        acc[i] += wv2 * h4[2];
        acc[i] += wv3 * h4[3];
      }
    }
  }

  const int b = r0 >> 11;               // /2048
  const int qloc = (r0 & 2047) + wid * 8;

  // s: rowsum via full-wave shuffle reduce (each wave owns 8 rows; every lane
  // holds a 4-col partial of every row)
#pragma unroll
  for (int i = 0; i < 8; ++i) {
    float p = acc[i][0] + acc[i][1] + acc[i][2] + acc[i][3];
#pragma unroll
    for (int off = 1; off < 64; off <<= 1) p += __shfl_xor(p, off, 64);
    if (lane == 0) s[r0 + wid * 8 + i] = p;
  }

  // WhT bf16: thread owns rows (q) [qloc, qloc+8), cols c..c+3
#pragma unroll
  for (int j = 0; j < 4; ++j) {
    u32x4 uv;
#pragma unroll
    for (int k2 = 0; k2 < 4; ++k2) {
      uv[k2] = (unsigned)f2bf(acc[2 * k2][j]) |
               ((unsigned)f2bf(acc[2 * k2 + 1][j]) << 16);
    }
    const size_t off = ((size_t)b * 256 + (c + j)) * 2048 + qloc;
    *(u32x4*)&WhT[off] = uv;
  }
}

// ---------------------------------------------------------------------------
// Kernel B: fused masked-softmax + PV matmul (flash-style online softmax).
// Block = one batch b, 32 p-rows; 4 waves x 64 o-cols each; q-tiles of 64.
// ---------------------------------------------------------------------------
__global__ __launch_bounds__(256, 2) void gat_attn(
    const int* __restrict__ adj, const float* __restrict__ s,
    const __hip_bfloat16* __restrict__ WhT, float* __restrict__ out)
{
  const int N = 2048;
  const int b = blockIdx.x >> 6;
  const int p0 = (blockIdx.x & 63) * 32;
  const int t = threadIdx.x;
  const int wid = t >> 6, lane = t & 63;

  // Bs: WhT tile [256 o][64 q] bf16, row stride 128B, XOR-swizzled (T2).
  // Wt: w tile  [32 p][64 q] bf16, same swizzle.
  __shared__ __align__(16) unsigned char Bs[256 * 128];
  __shared__ __align__(16) unsigned char Wt[32 * 128];
  __shared__ float m_sh[32], fac_sh[32], l_sh[32];

  const int ep = t >> 3;          // p-row this thread scores (0..31)
  const int eq8 = (t & 7) * 8;    // q-offset within tile (8 q per thread)
  const bool rowner = (t & 7) == 0;
  const float s_p = s[b * N + p0 + ep];
  const int* __restrict__ adjrow = adj + (size_t)(b * N + p0 + ep) * N;
  const __hip_bfloat16* __restrict__ WhTb = WhT + (size_t)b * 256 * 2048;

  const int so = t >> 3;          // Bs staging: o-row base
  const int q16 = t & 7;          // 16B chunk index within 128B o-row

  if (t < 32) { m_sh[t] = NEG_BIG; l_sh[t] = 0.f; fac_sh[t] = 0.f; }
  __syncthreads();

  f32x4 acc[2][4];
#pragma unroll
  for (int pt = 0; pt < 2; ++pt)
#pragma unroll
    for (int ot = 0; ot < 4; ++ot) acc[pt][ot] = (f32x4)(0.f);

  for (int q0 = 0; q0 < N; q0 += 64) {
    // --- issue WhT tile loads (to regs; LDS write after barrier) ---
    u32x4 breg[8];
#pragma unroll
    for (int j = 0; j < 8; ++j) {
      const int o = so + 32 * j;
      breg[j] = *(const u32x4*)&WhTb[(size_t)o * 2048 + q0 + q16 * 8];
    }

    // --- scores e = leaky(s_p+s_q) masked by adj ---
    const i32x4 a0 = *(const i32x4*)&adjrow[q0 + eq8];
    const i32x4 a1 = *(const i32x4*)&adjrow[q0 + eq8 + 4];
    const f32x4 sq0 = *(const f32x4*)&s[b * N + q0 + eq8];
    const f32x4 sq1 = *(const f32x4*)&s[b * N + q0 + eq8 + 4];
    float sqv[8] = {sq0[0], sq0[1], sq0[2], sq0[3],
                    sq1[0], sq1[1], sq1[2], sq1[3]};
    int av[8] = {a0[0], a0[1], a0[2], a0[3], a1[0], a1[1], a1[2], a1[3]};
    float ev[8];
#pragma unroll
    for (int i = 0; i < 8; ++i) {
      const float x = s_p + sqv[i];
      const float le = (x > 0.f) ? x : (LEAKY_ALPHA * x);
      ev[i] = (av[i] != 0) ? le : NEG_BIG;
    }
    float tm = ev[0];
#pragma unroll
    for (int i = 1; i < 8; ++i) tm = fmaxf(tm, ev[i]);
    tm = fmaxf(tm, __shfl_xor(tm, 1, 64));   // 8 threads/row are wave-local
    tm = fmaxf(tm, __shfl_xor(tm, 2, 64));
    tm = fmaxf(tm, __shfl_xor(tm, 4, 64));

    const float mo = m_sh[ep];       // written only by this wave's owner
    const float mn = fmaxf(mo, tm);

    float wv[8];
    float ls = 0.f;
#pragma unroll
    for (int i = 0; i < 8; ++i) {
      const float x = (ev[i] > 0.5f * NEG_BIG) ? __expf(ev[i] - mn) : 0.f;
      wv[i] = x;
      ls += x;
    }
    ls += __shfl_xor(ls, 1, 64);
    ls += __shfl_xor(ls, 2, 64);
    ls += __shfl_xor(ls, 4, 64);

    __syncthreads();  // barrier 1: previous tile's MFMA reads are done

    // --- write Bs (swizzled) ---
#pragma unroll
    for (int j = 0; j < 8; ++j) {
      const int o = so + 32 * j;
      const int byteoff = o * 128 + ((q16 * 16) ^ ((o & 7) << 4));
      *(u32x4*)&Bs[byteoff] = breg[j];
    }
    // --- write w tile bf16 (swizzled) ---
    {
      u32x4 pw;
#pragma unroll
      for (int k2 = 0; k2 < 4; ++k2)
        pw[k2] = (unsigned)f2bf(wv[2 * k2]) |
                 ((unsigned)f2bf(wv[2 * k2 + 1]) << 16);
      const int byteoff = ep * 128 + ((eq8 * 2) ^ ((ep & 7) << 4));
      *(u32x4*)&Wt[byteoff] = pw;
    }
    if (rowner) {
      const float fc = (mo > 0.5f * NEG_BIG) ? __expf(mo - mn) : 0.f;
      m_sh[ep] = mn;
      fac_sh[ep] = fc;
      l_sh[ep] = l_sh[ep] * fc + ls;
    }
    __syncthreads();  // barrier 2: Bs/Wt/fac visible

    // --- rescale accumulators by exp(m_old - m_new) per p-row ---
#pragma unroll
    for (int pt = 0; pt < 2; ++pt) {
      float f[4];
#pragma unroll
      for (int r = 0; r < 4; ++r)
        f[r] = fac_sh[pt * 16 + (lane >> 4) * 4 + r];
#pragma unroll
      for (int ot = 0; ot < 4; ++ot)
#pragma unroll
        for (int r = 0; r < 4; ++r) acc[pt][ot][r] *= f[r];
    }

    // --- MFMA: acc[p][o] += w[p][q] * Wh[q][o] ---
    s16x8 afrag[2][2];
#pragma unroll
    for (int pt = 0; pt < 2; ++pt)
#pragma unroll
      for (int kt = 0; kt < 2; ++kt) {
        const int pa = pt * 16 + (lane & 15);
        const int qb = kt * 64 + ((lane >> 4) << 4);
        afrag[pt][kt] =
            *(const s16x8*)&Wt[pa * 128 + (qb ^ ((pa & 7) << 4))];
      }
    s16x8 bfrag[4][2];
#pragma unroll
    for (int ot = 0; ot < 4; ++ot)
#pragma unroll
      for (int kt = 0; kt < 2; ++kt) {
        const int ob = wid * 64 + ot * 16 + (lane & 15);
        const int qb = kt * 64 + ((lane >> 4) << 4);
        bfrag[ot][kt] =
            *(const s16x8*)&Bs[ob * 128 + (qb ^ ((ob & 7) << 4))];
      }
#pragma unroll
    for (int pt = 0; pt < 2; ++pt)
#pragma unroll
      for (int ot = 0; ot < 4; ++ot)
#pragma unroll
        for (int kt = 0; kt < 2; ++kt)
          acc[pt][ot] = __builtin_amdgcn_mfma_f32_16x16x32_bf16(
              afrag[pt][kt], bfrag[ot][kt], acc[pt][ot], 0, 0, 0);
  }

  // --- epilogue: divide by l, store fp32 ---
#pragma unroll
  for (int pt = 0; pt < 2; ++pt) {
    float inv[4];
#pragma unroll
    for (int r = 0; r < 4; ++r)
      inv[r] = 1.f / l_sh[pt * 16 + (lane >> 4) * 4 + r];
#pragma unroll
    for (int ot = 0; ot < 4; ++ot) {
      const int o = wid * 64 + ot * 16 + (lane & 15);
#pragma unroll
      for (int r = 0; r < 4; ++r) {
        const int row = p0 + pt * 16 + (lane >> 4) * 4 + r;
        out[((size_t)b * N + row) * 256 + o] = acc[pt][ot][r] * inv[r];
      }
    }
  }
}

extern "C" void kernel_launch(void* const* d_in, const int* in_sizes, int n_in,
                              void* d_out, int out_size, void* d_ws, size_t ws_size,
                              hipStream_t stream) {
  const float* h = (const float*)d_in[0];
  const int* adj = (const int*)d_in[1];
  const float* W = (const float*)d_in[2];
  float* out = (float*)d_out;

  __hip_bfloat16* WhT = (__hip_bfloat16*)d_ws;                       // 8 MiB
  float* s = (float*)((char*)d_ws + (size_t)8 * 256 * 2048 * 2);     // 64 KiB

  gat_wh<<<512, 256, 0, stream>>>(h, W, WhT, s);
  gat_attn<<<8 * 64, 256, 0, stream>>>(adj, s, WhT, out);
}

// Round 2
// 76.131 us; speedup vs baseline: 1.4353x; 1.4353x over previous
//
#include <hip/hip_runtime.h>
#include <hip/hip_bf16.h>
#include <stdint.h>

#define LEAKY_ALPHA 0.2f
#define NEG_BIG (-1e30f)

using f32x4 = __attribute__((ext_vector_type(4))) float;
using u32x2 = __attribute__((ext_vector_type(2))) unsigned int;
using u32x4 = __attribute__((ext_vector_type(4))) unsigned int;
using i32x4 = __attribute__((ext_vector_type(4))) int;
using s16x8 = __attribute__((ext_vector_type(8))) short;

static __device__ __forceinline__ unsigned short f2bf(float x) {
  __hip_bfloat16 b = __float2bfloat16(x);
  return __builtin_bit_cast(unsigned short, b);
}

// ---------------------------------------------------------------------------
// Prep: WT[o][f] = bf16(W[f][o]);  wsum[f] = sum_o W[f][o]  (for exact fp32 s)
// ---------------------------------------------------------------------------
__global__ __launch_bounds__(256) void gat_prep(
    const float* __restrict__ W, __hip_bfloat16* __restrict__ WT,
    float* __restrict__ wsum)
{
  const int o = blockIdx.x;   // doubles as f-row index for wsum
  const int t = threadIdx.x;  // 256
  WT[o * 256 + t] = __float2bfloat16(W[t * 256 + o]);
  float u = W[o * 256 + t];
#pragma unroll
  for (int off = 1; off < 64; off <<= 1) u += __shfl_xor(u, off, 64);
  __shared__ float red[4];
  if ((t & 63) == 0) red[t >> 6] = u;
  __syncthreads();
  if (t == 0) wsum[o] = red[0] + red[1] + red[2] + red[3];
}

// ---------------------------------------------------------------------------
// Kernel A: WhT[b][o][q] = bf16( (h @ W)^T ) via MFMA; s[b][q] = h[q,:]·wsum
// (fp32 exact). Block = 64 q x 256 o, K=256 in 4 f-tiles. 256 blocks x 256 thr.
// ---------------------------------------------------------------------------
__global__ __launch_bounds__(256) void gat_wh2(
    const float* __restrict__ h, const __hip_bfloat16* __restrict__ WT,
    const float* __restrict__ wsum, __hip_bfloat16* __restrict__ WhT,
    float* __restrict__ s)
{
  const int b = blockIdx.x >> 5;
  const int q0 = (blockIdx.x & 31) * 64;
  const int t = threadIdx.x;
  const int wid = t >> 6, lane = t & 63;

  __shared__ __align__(16) unsigned char Bh[64 * 512];   // h bf16 [64q][256f] swz
  __shared__ __align__(16) unsigned char Aw[256 * 128];  // WT bf16 [256o][64f] swz
  __shared__ __align__(16) float wsl[256];

  wsl[t] = wsum[t];
  __syncthreads();

  // stage h -> Bh (bf16, swizzled) with fused fp32 s computation
  {
    const int q = t >> 2;
    const int fs = (t & 3) * 64;
    const float* hrow = h + ((size_t)(b * 2048 + q0 + q)) * 256 + fs;
    float sp = 0.f;
#pragma unroll
    for (int c = 0; c < 8; ++c) {
      const f32x4 a  = *(const f32x4*)&hrow[c * 8];
      const f32x4 bq = *(const f32x4*)&hrow[c * 8 + 4];
      const f32x4 wa = *(const f32x4*)&wsl[fs + c * 8];
      const f32x4 wb = *(const f32x4*)&wsl[fs + c * 8 + 4];
      sp += a[0]*wa[0] + a[1]*wa[1] + a[2]*wa[2] + a[3]*wa[3]
          + bq[0]*wb[0] + bq[1]*wb[1] + bq[2]*wb[2] + bq[3]*wb[3];
      u32x4 pk;
      pk[0] = (unsigned)f2bf(a[0])  | ((unsigned)f2bf(a[1])  << 16);
      pk[1] = (unsigned)f2bf(a[2])  | ((unsigned)f2bf(a[3])  << 16);
      pk[2] = (unsigned)f2bf(bq[0]) | ((unsigned)f2bf(bq[1]) << 16);
      pk[3] = (unsigned)f2bf(bq[2]) | ((unsigned)f2bf(bq[3]) << 16);
      const int boff = q * 512 + ((fs * 2 + c * 16) ^ ((q & 7) << 4));
      *(u32x4*)&Bh[boff] = pk;
    }
    sp += __shfl_xor(sp, 1, 64);
    sp += __shfl_xor(sp, 2, 64);
    if ((t & 3) == 0) s[b * 2048 + q0 + q] = sp;
  }

  f32x4 acc[4][4];
#pragma unroll
  for (int i = 0; i < 4; ++i)
#pragma unroll
    for (int j = 0; j < 4; ++j) acc[i][j] = (f32x4)(0.f);

  for (int it = 0; it < 4; ++it) {
    const int f0 = it * 64;
    __syncthreads();   // it=0: Bh visible; it>0: protect Aw from prev reads
#pragma unroll
    for (int j = 0; j < 8; ++j) {
      const int o = (t >> 3) + 32 * j;
      const int c = t & 7;
      const u32x4 v = *(const u32x4*)&WT[o * 256 + f0 + c * 8];
      *(u32x4*)&Aw[o * 128 + ((c * 16) ^ ((o & 7) << 4))] = v;
    }
    __syncthreads();
#pragma unroll
    for (int kt = 0; kt < 2; ++kt) {
      const int kb = kt * 64 + ((lane >> 4) << 4);   // byte off within 64-f span
      s16x8 af[4], bf[4];
#pragma unroll
      for (int qt = 0; qt < 4; ++qt) {
        const int qr = qt * 16 + (lane & 15);
        af[qt] = *(const s16x8*)&Bh[qr * 512 + ((f0 * 2 + kb) ^ ((qr & 7) << 4))];
      }
#pragma unroll
      for (int ot = 0; ot < 4; ++ot) {
        const int orow = wid * 64 + ot * 16 + (lane & 15);
        bf[ot] = *(const s16x8*)&Aw[orow * 128 + (kb ^ ((orow & 7) << 4))];
      }
#pragma unroll
      for (int qt = 0; qt < 4; ++qt)
#pragma unroll
        for (int ot = 0; ot < 4; ++ot)
          acc[qt][ot] = __builtin_amdgcn_mfma_f32_16x16x32_bf16(
              af[qt], bf[ot], acc[qt][ot], 0, 0, 0);
    }
  }

  // epilogue: WhT[b][o][q0+q]; C-row = q (r contiguous) -> 8B vector stores
  __hip_bfloat16* __restrict__ WhTb = WhT + (size_t)b * 256 * 2048;
#pragma unroll
  for (int qt = 0; qt < 4; ++qt)
#pragma unroll
    for (int ot = 0; ot < 4; ++ot) {
      const int o = wid * 64 + ot * 16 + (lane & 15);
      const int ql = q0 + qt * 16 + ((lane >> 4) << 2);
      u32x2 pk;
      pk[0] = (unsigned)f2bf(acc[qt][ot][0]) | ((unsigned)f2bf(acc[qt][ot][1]) << 16);
      pk[1] = (unsigned)f2bf(acc[qt][ot][2]) | ((unsigned)f2bf(acc[qt][ot][3]) << 16);
      *(u32x2*)&WhTb[(size_t)o * 2048 + ql] = pk;
    }
}

// ---------------------------------------------------------------------------
// Kernel B: fused masked-softmax + PV (flash-style). Block = batch-slice,
// 32 p-rows, 512 thr (8 waves x 32 o-cols). Reg-prefetch next tile across
// raw barriers (lgkm-only drain) so vmem stays in flight (T14).
// ---------------------------------------------------------------------------
__global__ __launch_bounds__(512, 4) void gat_attn(
    const int* __restrict__ adj, const float* __restrict__ s,
    const __hip_bfloat16* __restrict__ WhT, float* __restrict__ out)
{
  const int N = 2048;
  const int bid = blockIdx.x;
  const int swz = (bid & 7) * 64 + (bid >> 3);   // XCD-major: batch == XCD
  const int b = swz >> 6;
  const int p0 = (swz & 63) * 32;
  const int t = threadIdx.x;
  const int wid = t >> 6, lane = t & 63;

  __shared__ __align__(16) unsigned char Bs[256 * 128];  // WhT tile [256o][64q] swz
  __shared__ __align__(16) unsigned char Wt[32 * 128];   // P tile  [32p][64q] swz
  __shared__ __align__(16) float m_sh[32];
  __shared__ __align__(16) float fac_sh[32];
  __shared__ __align__(16) float l_sh[32];

  const int ep = t >> 4;              // p-row 0..31 (16 thr/row)
  const int eq4 = (t & 15) * 4;       // 4 q per thread
  const bool rowner = (t & 15) == 0;
  const float s_p = s[b * N + p0 + ep];
  const int* __restrict__ adjrow = adj + ((size_t)(b * N + p0 + ep)) * N;
  const float* __restrict__ sB = s + b * N;
  const __hip_bfloat16* __restrict__ WhTb = WhT + (size_t)b * 256 * 2048;

  const int so = t >> 3;              // Bs staging o-base 0..63
  const int q16 = t & 7;              // 16B chunk in 128B row

  if (t < 32) { m_sh[t] = NEG_BIG; l_sh[t] = 0.f; fac_sh[t] = 0.f; }

  f32x4 acc[2][2];
#pragma unroll
  for (int pt = 0; pt < 2; ++pt)
#pragma unroll
    for (int ot = 0; ot < 2; ++ot) acc[pt][ot] = (f32x4)(0.f);

  __syncthreads();

  // prologue: prefetch tile 0 into regs
  i32x4 av = *(const i32x4*)&adjrow[eq4];
  f32x4 sv = *(const f32x4*)&sB[eq4];
  u32x4 breg[4];
#pragma unroll
  for (int j = 0; j < 4; ++j)
    breg[j] = *(const u32x4*)&WhTb[(size_t)(so + 64 * j) * 2048 + q16 * 8];

  for (int q0 = 0; q0 < N; q0 += 64) {
    // ---- scores from prefetched regs ----
    float ev[4];
#pragma unroll
    for (int i = 0; i < 4; ++i) {
      const float x = s_p + sv[i];
      const float le = (x > 0.f) ? x : (LEAKY_ALPHA * x);
      ev[i] = (av[i] != 0) ? le : NEG_BIG;
    }
    float tm = fmaxf(fmaxf(ev[0], ev[1]), fmaxf(ev[2], ev[3]));
    tm = fmaxf(tm, __shfl_xor(tm, 1, 64));
    tm = fmaxf(tm, __shfl_xor(tm, 2, 64));
    tm = fmaxf(tm, __shfl_xor(tm, 4, 64));
    tm = fmaxf(tm, __shfl_xor(tm, 8, 64));
    const float mo = m_sh[ep];
    const float mn = fmaxf(mo, tm);
    float wv[4];
    float ls = 0.f;
#pragma unroll
    for (int i = 0; i < 4; ++i) {
      const float x = (ev[i] > 0.5f * NEG_BIG) ? __expf(ev[i] - mn) : 0.f;
      wv[i] = x;
      ls += x;
    }
    ls += __shfl_xor(ls, 1, 64);
    ls += __shfl_xor(ls, 2, 64);
    ls += __shfl_xor(ls, 4, 64);
    ls += __shfl_xor(ls, 8, 64);

    // ---- barrier 1 (raw, no drain): prev MFMA frag reads already complete --
    asm volatile("" ::: "memory");
    __builtin_amdgcn_s_barrier();
    asm volatile("" ::: "memory");

    // ---- write Bs / Wt / row state ----
#pragma unroll
    for (int j = 0; j < 4; ++j) {
      const int o = so + 64 * j;
      *(u32x4*)&Bs[o * 128 + ((q16 * 16) ^ ((o & 7) << 4))] = breg[j];
    }
    {
      u32x2 pw;
      pw[0] = (unsigned)f2bf(wv[0]) | ((unsigned)f2bf(wv[1]) << 16);
      pw[1] = (unsigned)f2bf(wv[2]) | ((unsigned)f2bf(wv[3]) << 16);
      *(u32x2*)&Wt[ep * 128 + ((eq4 * 2) ^ ((ep & 7) << 4))] = pw;
    }
    if (rowner) {
      const float fc = (mo > 0.5f * NEG_BIG) ? __expf(mo - mn) : 0.f;
      m_sh[ep] = mn;
      fac_sh[ep] = fc;
      l_sh[ep] = l_sh[ep] * fc + ls;
    }

    // ---- prefetch next tile (stays in flight across barrier 2) ----
    const int qn = q0 + 64;
    if (qn < N) {
      av = *(const i32x4*)&adjrow[qn + eq4];
      sv = *(const f32x4*)&sB[qn + eq4];
#pragma unroll
      for (int j = 0; j < 4; ++j)
        breg[j] = *(const u32x4*)&WhTb[(size_t)(so + 64 * j) * 2048 + qn + q16 * 8];
    }

    // ---- barrier 2: drain LDS writes only (vmem prefetch stays in flight) --
    asm volatile("s_waitcnt lgkmcnt(0)" ::: "memory");
    __builtin_amdgcn_s_barrier();
    asm volatile("" ::: "memory");

    // ---- rescale accumulators ----
#pragma unroll
    for (int pt = 0; pt < 2; ++pt) {
      const f32x4 f = *(const f32x4*)&fac_sh[pt * 16 + ((lane >> 4) << 2)];
#pragma unroll
      for (int ot = 0; ot < 2; ++ot) acc[pt][ot] *= f;
    }

    // ---- fragments + MFMA ----
    s16x8 afr[2][2], bfr[2][2];
#pragma unroll
    for (int pt = 0; pt < 2; ++pt)
#pragma unroll
      for (int kt = 0; kt < 2; ++kt) {
        const int pa = pt * 16 + (lane & 15);
        const int kb = kt * 64 + ((lane >> 4) << 4);
        afr[pt][kt] = *(const s16x8*)&Wt[pa * 128 + (kb ^ ((pa & 7) << 4))];
      }
#pragma unroll
    for (int ot = 0; ot < 2; ++ot)
#pragma unroll
      for (int kt = 0; kt < 2; ++kt) {
        const int ob = wid * 32 + ot * 16 + (lane & 15);
        const int kb = kt * 64 + ((lane >> 4) << 4);
        bfr[ot][kt] = *(const s16x8*)&Bs[ob * 128 + (kb ^ ((ob & 7) << 4))];
      }
#pragma unroll
    for (int pt = 0; pt < 2; ++pt)
#pragma unroll
      for (int ot = 0; ot < 2; ++ot)
#pragma unroll
        for (int kt = 0; kt < 2; ++kt)
          acc[pt][ot] = __builtin_amdgcn_mfma_f32_16x16x32_bf16(
              afr[pt][kt], bfr[ot][kt], acc[pt][ot], 0, 0, 0);
  }

  // ---- epilogue: divide by l, store fp32 ----
#pragma unroll
  for (int pt = 0; pt < 2; ++pt) {
    const f32x4 lv = *(const f32x4*)&l_sh[pt * 16 + ((lane >> 4) << 2)];
    f32x4 inv;
#pragma unroll
    for (int r = 0; r < 4; ++r) inv[r] = 1.f / lv[r];
#pragma unroll
    for (int ot = 0; ot < 2; ++ot) {
      const int o = wid * 32 + ot * 16 + (lane & 15);
#pragma unroll
      for (int r = 0; r < 4; ++r) {
        const int row = p0 + pt * 16 + ((lane >> 4) << 2) + r;
        out[((size_t)(b * N + row)) * 256 + o] = acc[pt][ot][r] * inv[r];
      }
    }
  }
}

extern "C" void kernel_launch(void* const* d_in, const int* in_sizes, int n_in,
                              void* d_out, int out_size, void* d_ws, size_t ws_size,
                              hipStream_t stream) {
  const float* h = (const float*)d_in[0];
  const int* adj = (const int*)d_in[1];
  const float* W = (const float*)d_in[2];
  float* out = (float*)d_out;

  char* ws = (char*)d_ws;
  __hip_bfloat16* WhT = (__hip_bfloat16*)ws;                              // 8 MiB
  float* s = (float*)(ws + (size_t)8 * 1024 * 1024);                      // 64 KiB
  __hip_bfloat16* WT = (__hip_bfloat16*)(ws + (size_t)8 * 1024 * 1024 + 65536);   // 128 KiB
  float* wsum = (float*)(ws + (size_t)8 * 1024 * 1024 + 65536 + 131072);  // 1 KiB

  gat_prep<<<256, 256, 0, stream>>>(W, WT, wsum);
  gat_wh2<<<256, 256, 0, stream>>>(h, WT, wsum, WhT, s);
  gat_attn<<<512, 512, 0, stream>>>(adj, s, WhT, out);
}

// Round 3
// 57.233 us; speedup vs baseline: 1.9093x; 1.3302x over previous
//
#include <hip/hip_runtime.h>
#include <hip/hip_bf16.h>
#include <stdint.h>

#define LEAKY_ALPHA 0.2f

using f32x4 = __attribute__((ext_vector_type(4))) float;
using u32x2 = __attribute__((ext_vector_type(2))) unsigned int;
using u32x4 = __attribute__((ext_vector_type(4))) unsigned int;
using i32x4 = __attribute__((ext_vector_type(4))) int;
using s16x8 = __attribute__((ext_vector_type(8))) short;

static __device__ __forceinline__ unsigned short f2bf(float x) {
  __hip_bfloat16 b = __float2bfloat16(x);
  return __builtin_bit_cast(unsigned short, b);
}

// ---------------------------------------------------------------------------
// Prep: WT[o][f] = bf16(W[f][o]);  wsum[f] = sum_o W[f][o]  (for exact fp32 s)
// ---------------------------------------------------------------------------
__global__ __launch_bounds__(256) void gat_prep(
    const float* __restrict__ W, __hip_bfloat16* __restrict__ WT,
    float* __restrict__ wsum)
{
  const int o = blockIdx.x;   // doubles as f-row index for wsum
  const int t = threadIdx.x;  // 256
  WT[o * 256 + t] = __float2bfloat16(W[t * 256 + o]);
  float u = W[o * 256 + t];
#pragma unroll
  for (int off = 1; off < 64; off <<= 1) u += __shfl_xor(u, off, 64);
  __shared__ float red[4];
  if ((t & 63) == 0) red[t >> 6] = u;
  __syncthreads();
  if (t == 0) wsum[o] = red[0] + red[1] + red[2] + red[3];
}

// ---------------------------------------------------------------------------
// Kernel A: WhT[b][o][q] = bf16( (h @ W)^T ) via MFMA; s[b][q] = h[q,:]·wsum
// (fp32 exact). Block = 64 q x 256 o, K=256 in 4 f-tiles. 256 blocks x 256 thr.
// ---------------------------------------------------------------------------
__global__ __launch_bounds__(256) void gat_wh2(
    const float* __restrict__ h, const __hip_bfloat16* __restrict__ WT,
    const float* __restrict__ wsum, __hip_bfloat16* __restrict__ WhT,
    float* __restrict__ s)
{
  const int b = blockIdx.x >> 5;
  const int q0 = (blockIdx.x & 31) * 64;
  const int t = threadIdx.x;
  const int wid = t >> 6, lane = t & 63;

  __shared__ __align__(16) unsigned char Bh[64 * 512];   // h bf16 [64q][256f] swz
  __shared__ __align__(16) unsigned char Aw[256 * 128];  // WT bf16 [256o][64f] swz
  __shared__ __align__(16) float wsl[256];

  wsl[t] = wsum[t];
  __syncthreads();

  // stage h -> Bh (bf16, swizzled) with fused fp32 s computation
  {
    const int q = t >> 2;
    const int fs = (t & 3) * 64;
    const float* hrow = h + ((size_t)(b * 2048 + q0 + q)) * 256 + fs;
    float sp = 0.f;
#pragma unroll
    for (int c = 0; c < 8; ++c) {
      const f32x4 a  = *(const f32x4*)&hrow[c * 8];
      const f32x4 bq = *(const f32x4*)&hrow[c * 8 + 4];
      const f32x4 wa = *(const f32x4*)&wsl[fs + c * 8];
      const f32x4 wb = *(const f32x4*)&wsl[fs + c * 8 + 4];
      sp += a[0]*wa[0] + a[1]*wa[1] + a[2]*wa[2] + a[3]*wa[3]
          + bq[0]*wb[0] + bq[1]*wb[1] + bq[2]*wb[2] + bq[3]*wb[3];
      u32x4 pk;
      pk[0] = (unsigned)f2bf(a[0])  | ((unsigned)f2bf(a[1])  << 16);
      pk[1] = (unsigned)f2bf(a[2])  | ((unsigned)f2bf(a[3])  << 16);
      pk[2] = (unsigned)f2bf(bq[0]) | ((unsigned)f2bf(bq[1]) << 16);
      pk[3] = (unsigned)f2bf(bq[2]) | ((unsigned)f2bf(bq[3]) << 16);
      const int boff = q * 512 + ((fs * 2 + c * 16) ^ ((q & 7) << 4));
      *(u32x4*)&Bh[boff] = pk;
    }
    sp += __shfl_xor(sp, 1, 64);
    sp += __shfl_xor(sp, 2, 64);
    if ((t & 3) == 0) s[b * 2048 + q0 + q] = sp;
  }

  f32x4 acc[4][4];
#pragma unroll
  for (int i = 0; i < 4; ++i)
#pragma unroll
    for (int j = 0; j < 4; ++j) acc[i][j] = (f32x4)(0.f);

  for (int it = 0; it < 4; ++it) {
    const int f0 = it * 64;
    __syncthreads();   // it=0: Bh visible; it>0: protect Aw from prev reads
#pragma unroll
    for (int j = 0; j < 8; ++j) {
      const int o = (t >> 3) + 32 * j;
      const int c = t & 7;
      const u32x4 v = *(const u32x4*)&WT[o * 256 + f0 + c * 8];
      *(u32x4*)&Aw[o * 128 + ((c * 16) ^ ((o & 7) << 4))] = v;
    }
    __syncthreads();
#pragma unroll
    for (int kt = 0; kt < 2; ++kt) {
      const int kb = kt * 64 + ((lane >> 4) << 4);   // byte off within 64-f span
      s16x8 af[4], bf[4];
#pragma unroll
      for (int qt = 0; qt < 4; ++qt) {
        const int qr = qt * 16 + (lane & 15);
        af[qt] = *(const s16x8*)&Bh[qr * 512 + ((f0 * 2 + kb) ^ ((qr & 7) << 4))];
      }
#pragma unroll
      for (int ot = 0; ot < 4; ++ot) {
        const int orow = wid * 64 + ot * 16 + (lane & 15);
        bf[ot] = *(const s16x8*)&Aw[orow * 128 + (kb ^ ((orow & 7) << 4))];
      }
#pragma unroll
      for (int qt = 0; qt < 4; ++qt)
#pragma unroll
        for (int ot = 0; ot < 4; ++ot)
          acc[qt][ot] = __builtin_amdgcn_mfma_f32_16x16x32_bf16(
              af[qt], bf[ot], acc[qt][ot], 0, 0, 0);
    }
  }

  // epilogue: WhT[b][o][q0+q]; C-row = q (r contiguous) -> 8B vector stores
  __hip_bfloat16* __restrict__ WhTb = WhT + (size_t)b * 256 * 2048;
#pragma unroll
  for (int qt = 0; qt < 4; ++qt)
#pragma unroll
    for (int ot = 0; ot < 4; ++ot) {
      const int o = wid * 64 + ot * 16 + (lane & 15);
      const int ql = q0 + qt * 16 + ((lane >> 4) << 2);
      u32x2 pk;
      pk[0] = (unsigned)f2bf(acc[qt][ot][0]) | ((unsigned)f2bf(acc[qt][ot][1]) << 16);
      pk[1] = (unsigned)f2bf(acc[qt][ot][2]) | ((unsigned)f2bf(acc[qt][ot][3]) << 16);
      *(u32x2*)&WhTb[(size_t)o * 2048 + ql] = pk;
    }
}

// ---------------------------------------------------------------------------
// Kernel B: fused masked-softmax + PV. Fixed per-row max bound
// m_p = leaky(s_p + max_q s_q)  (leaky is monotone => valid upper bound;
// scale cancels exactly in the final division) -> NO online rescale, no
// in-loop shuffles. Double-buffered LDS, ONE raw barrier (lgkm drain) per
// 64-q tile, reg-prefetch next tile across the barrier.
// ---------------------------------------------------------------------------
__global__ __launch_bounds__(512, 4) void gat_attn(
    const int* __restrict__ adj, const float* __restrict__ s,
    const __hip_bfloat16* __restrict__ WhT, float* __restrict__ out)
{
  const int N = 2048;
  const int bid = blockIdx.x;
  const int swz = (bid & 7) * 64 + (bid >> 3);   // XCD-major: batch == XCD
  const int b = swz >> 6;
  const int p0 = (swz & 63) * 32;
  const int t = threadIdx.x;
  const int wid = t >> 6, lane = t & 63;

  __shared__ __align__(16) unsigned char Bs[2][256 * 128]; // WhT tile dbuf
  __shared__ __align__(16) unsigned char Wt[2][32 * 128];  // P tile dbuf
  __shared__ __align__(16) float red_sh[8];
  __shared__ __align__(16) float l_sh[32];

  const int ep = t >> 4;              // p-row 0..31 (16 thr/row)
  const int eq4 = (t & 15) * 4;       // 4 q per thread
  const int* __restrict__ adjrow = adj + ((size_t)(b * N + p0 + ep)) * N;
  const float* __restrict__ sB = s + b * N;
  const __hip_bfloat16* __restrict__ WhTb = WhT + (size_t)b * 256 * 2048;

  const int so = t >> 3;              // Bs staging o-base 0..63
  const int q16 = t & 7;              // 16B chunk in 128B row

  // ---- prologue: prefetch tile 0 into regs ----
  i32x4 av = *(const i32x4*)&adjrow[eq4];
  f32x4 sv = *(const f32x4*)&sB[eq4];
  u32x4 breg[4];
#pragma unroll
  for (int j = 0; j < 4; ++j)
    breg[j] = *(const u32x4*)&WhTb[(size_t)(so + 64 * j) * 2048 + q16 * 8];

  // ---- block-wide smax over s[b,:] (fixed softmax bound) ----
  const f32x4 s4 = *(const f32x4*)&sB[t * 4];
  float bm = fmaxf(fmaxf(s4[0], s4[1]), fmaxf(s4[2], s4[3]));
#pragma unroll
  for (int off = 1; off < 64; off <<= 1) bm = fmaxf(bm, __shfl_xor(bm, off, 64));
  if (lane == 0) red_sh[wid] = bm;
  const float s_p = sB[p0 + ep];
  __syncthreads();
  float smax = red_sh[0];
#pragma unroll
  for (int k = 1; k < 8; ++k) smax = fmaxf(smax, red_sh[k]);
  const float xm = s_p + smax;
  const float m_p = (xm > 0.f) ? xm : (LEAKY_ALPHA * xm);

  f32x4 acc[2][2];
#pragma unroll
  for (int pt = 0; pt < 2; ++pt)
#pragma unroll
    for (int ot = 0; ot < 2; ++ot) acc[pt][ot] = (f32x4)(0.f);
  float lacc = 0.f;

#define GAT_TILE(BI, QQ)                                                      \
  do {                                                                        \
    float wv[4];                                                              \
    _Pragma("unroll")                                                         \
    for (int i = 0; i < 4; ++i) {                                             \
      const float x = s_p + sv[i];                                            \
      const float le = (x > 0.f) ? x : (LEAKY_ALPHA * x);                     \
      const float w = __expf(le - m_p);                                       \
      wv[i] = (av[i] != 0) ? w : 0.f;                                         \
      lacc += wv[i];                                                          \
    }                                                                         \
    {                                                                         \
      u32x2 pw;                                                               \
      pw[0] = (unsigned)f2bf(wv[0]) | ((unsigned)f2bf(wv[1]) << 16);          \
      pw[1] = (unsigned)f2bf(wv[2]) | ((unsigned)f2bf(wv[3]) << 16);          \
      *(u32x2*)&Wt[BI][ep * 128 + ((eq4 * 2) ^ ((ep & 7) << 4))] = pw;        \
    }                                                                         \
    _Pragma("unroll")                                                         \
    for (int j = 0; j < 4; ++j) {                                             \
      const int o = so + 64 * j;                                              \
      *(u32x4*)&Bs[BI][o * 128 + ((q16 * 16) ^ ((o & 7) << 4))] = breg[j];    \
    }                                                                         \
    if ((QQ) + 64 < N) {                                                      \
      av = *(const i32x4*)&adjrow[(QQ) + 64 + eq4];                           \
      sv = *(const f32x4*)&sB[(QQ) + 64 + eq4];                               \
      _Pragma("unroll")                                                       \
      for (int j = 0; j < 4; ++j)                                             \
        breg[j] = *(const u32x4*)&WhTb[(size_t)(so + 64 * j) * 2048 +         \
                                       (QQ) + 64 + q16 * 8];                  \
    }                                                                         \
    asm volatile("s_waitcnt lgkmcnt(0)" ::: "memory");                        \
    __builtin_amdgcn_s_barrier();                                             \
    asm volatile("" ::: "memory");                                            \
    {                                                                         \
      s16x8 afr[2][2], bfr[2][2];                                             \
      _Pragma("unroll")                                                       \
      for (int pt = 0; pt < 2; ++pt)                                          \
        _Pragma("unroll")                                                     \
        for (int kt = 0; kt < 2; ++kt) {                                      \
          const int pa = pt * 16 + (lane & 15);                               \
          const int kb = kt * 64 + ((lane >> 4) << 4);                        \
          afr[pt][kt] =                                                       \
              *(const s16x8*)&Wt[BI][pa * 128 + (kb ^ ((pa & 7) << 4))];      \
        }                                                                     \
      _Pragma("unroll")                                                       \
      for (int ot = 0; ot < 2; ++ot)                                          \
        _Pragma("unroll")                                                     \
        for (int kt = 0; kt < 2; ++kt) {                                      \
          const int ob = wid * 32 + ot * 16 + (lane & 15);                    \
          const int kb = kt * 64 + ((lane >> 4) << 4);                        \
          bfr[ot][kt] =                                                       \
              *(const s16x8*)&Bs[BI][ob * 128 + (kb ^ ((ob & 7) << 4))];      \
        }                                                                     \
      _Pragma("unroll")                                                       \
      for (int pt = 0; pt < 2; ++pt)                                          \
        _Pragma("unroll")                                                     \
        for (int ot = 0; ot < 2; ++ot)                                        \
          _Pragma("unroll")                                                   \
          for (int kt = 0; kt < 2; ++kt)                                      \
            acc[pt][ot] = __builtin_amdgcn_mfma_f32_16x16x32_bf16(            \
                afr[pt][kt], bfr[ot][kt], acc[pt][ot], 0, 0, 0);              \
    }                                                                         \
  } while (0)

  for (int q0 = 0; q0 < N; q0 += 128) {
    GAT_TILE(0, q0);
    GAT_TILE(1, q0 + 64);
  }
#undef GAT_TILE

  // ---- l reduction: 16 threads per row -> l_sh ----
  lacc += __shfl_xor(lacc, 1, 64);
  lacc += __shfl_xor(lacc, 2, 64);
  lacc += __shfl_xor(lacc, 4, 64);
  lacc += __shfl_xor(lacc, 8, 64);
  if ((t & 15) == 0) l_sh[ep] = lacc;
  __syncthreads();

  // ---- epilogue: divide by l, store fp32 ----
#pragma unroll
  for (int pt = 0; pt < 2; ++pt) {
    const f32x4 lv = *(const f32x4*)&l_sh[pt * 16 + ((lane >> 4) << 2)];
    f32x4 inv;
#pragma unroll
    for (int r = 0; r < 4; ++r) inv[r] = 1.f / lv[r];
#pragma unroll
    for (int ot = 0; ot < 2; ++ot) {
      const int o = wid * 32 + ot * 16 + (lane & 15);
#pragma unroll
      for (int r = 0; r < 4; ++r) {
        const int row = p0 + pt * 16 + ((lane >> 4) << 2) + r;
        out[((size_t)(b * N + row)) * 256 + o] = acc[pt][ot][r] * inv[r];
      }
    }
  }
}

extern "C" void kernel_launch(void* const* d_in, const int* in_sizes, int n_in,
                              void* d_out, int out_size, void* d_ws, size_t ws_size,
                              hipStream_t stream) {
  const float* h = (const float*)d_in[0];
  const int* adj = (const int*)d_in[1];
  const float* W = (const float*)d_in[2];
  float* out = (float*)d_out;

  char* ws = (char*)d_ws;
  __hip_bfloat16* WhT = (__hip_bfloat16*)ws;                              // 8 MiB
  float* s = (float*)(ws + (size_t)8 * 1024 * 1024);                      // 64 KiB
  __hip_bfloat16* WT = (__hip_bfloat16*)(ws + (size_t)8 * 1024 * 1024 + 65536);   // 128 KiB
  float* wsum = (float*)(ws + (size_t)8 * 1024 * 1024 + 65536 + 131072);  // 1 KiB

  gat_prep<<<256, 256, 0, stream>>>(W, WT, wsum);
  gat_wh2<<<256, 256, 0, stream>>>(h, WT, wsum, WhT, s);
  gat_attn<<<512, 512, 0, stream>>>(adj, s, WhT, out);
}